// Round 11
// baseline (353.662 us; speedup 1.0000x reference)
//
#include <hip/hip_runtime.h>
#include <hip/hip_bf16.h>

typedef __attribute__((ext_vector_type(8))) short short8;
typedef __attribute__((ext_vector_type(4))) float f32x4;
typedef __attribute__((ext_vector_type(4))) unsigned short ushort4v;

static __device__ __forceinline__ unsigned short f2bf(float f) {
  unsigned u = __float_as_uint(f);
  unsigned r = (u + 0x7fffu + ((u >> 16) & 1u)) >> 16;
  return (unsigned short)r;
}
static __device__ __forceinline__ short8 pack8(float4 a, float4 b) {
  short8 r;
  r[0] = (short)f2bf(a.x); r[1] = (short)f2bf(a.y);
  r[2] = (short)f2bf(a.z); r[3] = (short)f2bf(a.w);
  r[4] = (short)f2bf(b.x); r[5] = (short)f2bf(b.y);
  r[6] = (short)f2bf(b.z); r[7] = (short)f2bf(b.w);
  return r;
}

// DPP-based max over each 16-lane group (all lanes receive the result).
template <int CTRL>
static __device__ __forceinline__ float fmax_dpp(float x) {
  int t = __builtin_amdgcn_update_dpp(__float_as_int(x), __float_as_int(x),
                                      CTRL, 0xF, 0xF, true);
  return fmaxf(x, __int_as_float(t));
}
static __device__ __forceinline__ float max16_dpp(float x) {
  x = fmax_dpp<0xB1>(x);   // quad_perm xor1
  x = fmax_dpp<0x4E>(x);   // quad_perm xor2
  x = fmax_dpp<0x141>(x);  // row_half_mirror
  x = fmax_dpp<0x140>(x);  // row_mirror
  return x;
}

// ---------------------------------------------------------------------------
// 128x128-tile GEMM (unchanged)
// ---------------------------------------------------------------------------
template<int XF32, int OUTF32>
__device__ __forceinline__ void gemm128(
    const void* Xp, const float* W, const float* bias,
    void* outp, float scale, int vt_mode, int bm, int bn)
{
  __shared__ unsigned short Als[128 * 32];
  __shared__ unsigned short Bls[128 * 32];

  const int tid = threadIdx.x;
  const int wave = tid >> 6, lane = tid & 63;
  const int g = lane >> 4, lo = lane & 15;
  const int wr = wave >> 1, wc = wave & 1;
  const int m0 = bm * 128, n0 = bn * 128;

  const f32x4 vzero = {0.f, 0.f, 0.f, 0.f};
  f32x4 acc[4][4];
#pragma unroll
  for (int m = 0; m < 4; ++m)
#pragma unroll
    for (int n = 0; n < 4; ++n) acc[m][n] = vzero;

  const int arow = tid >> 1;
  const int acol = (tid & 1) * 16;
  const float* Af = nullptr;
  const unsigned short* Ab = nullptr;
  if constexpr (XF32) Af = (const float*)Xp + (size_t)(m0 + arow) * 768 + acol;
  else                Ab = (const unsigned short*)Xp + (size_t)(m0 + arow) * 768 + acol;
  const float* Brow = W + (size_t)(n0 + arow) * 768 + acol;

  for (int k0 = 0; k0 < 768; k0 += 32) {
    short8 va0, va1;
    if constexpr (XF32) {
      float4 f0 = *(const float4*)(Af + k0);
      float4 f1 = *(const float4*)(Af + k0 + 4);
      float4 f2 = *(const float4*)(Af + k0 + 8);
      float4 f3 = *(const float4*)(Af + k0 + 12);
      va0 = pack8(f0, f1);
      va1 = pack8(f2, f3);
    } else {
      va0 = *(const short8*)(Ab + k0);
      va1 = *(const short8*)(Ab + k0 + 8);
    }
    float4 g0 = *(const float4*)(Brow + k0);
    float4 g1 = *(const float4*)(Brow + k0 + 4);
    float4 g2 = *(const float4*)(Brow + k0 + 8);
    float4 g3 = *(const float4*)(Brow + k0 + 12);
    short8 vb0 = pack8(g0, g1);
    short8 vb1 = pack8(g2, g3);

    __syncthreads();
    *(short8*)(Als + arow * 32 + acol)     = va0;
    *(short8*)(Als + arow * 32 + acol + 8) = va1;
    *(short8*)(Bls + arow * 32 + acol)     = vb0;
    *(short8*)(Bls + arow * 32 + acol + 8) = vb1;
    __syncthreads();

    short8 af[4], bf[4];
#pragma unroll
    for (int m = 0; m < 4; ++m)
      af[m] = *(const short8*)(Als + (wr * 64 + m * 16 + lo) * 32 + g * 8);
#pragma unroll
    for (int n = 0; n < 4; ++n)
      bf[n] = *(const short8*)(Bls + (wc * 64 + n * 16 + lo) * 32 + g * 8);
#pragma unroll
    for (int m = 0; m < 4; ++m)
#pragma unroll
      for (int n = 0; n < 4; ++n)
        acc[m][n] = __builtin_amdgcn_mfma_f32_16x16x32_bf16(af[m], bf[n], acc[m][n], 0, 0, 0);
  }

#pragma unroll
  for (int n = 0; n < 4; ++n) {
    const int ncol = n0 + wc * 64 + n * 16 + lo;
    const float bb = bias[ncol];
#pragma unroll
    for (int m = 0; m < 4; ++m) {
      const int rowb = m0 + wr * 64 + m * 16 + g * 4;
      if constexpr (OUTF32) {
        float* out = (float*)outp;
#pragma unroll
        for (int r = 0; r < 4; ++r)
          out[(size_t)(rowb + r) * 768 + ncol] = (acc[m][n][r] + bb) * scale;
      } else {
        unsigned short* out = (unsigned short*)outp;
        if (!vt_mode) {
#pragma unroll
          for (int r = 0; r < 4; ++r)
            out[(size_t)(rowb + r) * 768 + ncol] = f2bf((acc[m][n][r] + bb) * scale);
        } else {
          const int b = rowb >> 12, s = rowb & 4095;
          const int hh = ncol >> 6, d = ncol & 63;
          ushort4v pk;
#pragma unroll
          for (int r = 0; r < 4; ++r) pk[r] = f2bf((acc[m][n][r] + bb) * scale);
          *(ushort4v*)(out + (((size_t)b * 12 + hh) * 64 + d) * 4096 + s) = pk;
        }
      }
    }
  }
}

__global__ __launch_bounds__(256, 2) void qkv_proj(
    const float* __restrict__ Qi, const float* __restrict__ Ki,
    const float* __restrict__ Vi,
    const float* __restrict__ Wq, const float* __restrict__ bq,
    const float* __restrict__ Wk, const float* __restrict__ bk,
    const float* __restrict__ Wv, const float* __restrict__ bv,
    unsigned short* __restrict__ qo, unsigned short* __restrict__ ko,
    unsigned short* __restrict__ vto)
{
  const int z = blockIdx.z;
  const float* X = (z == 0) ? Qi : (z == 1) ? Ki : Vi;
  const float* W = (z == 0) ? Wq : (z == 1) ? Wk : Wv;
  const float* bb = (z == 0) ? bq : (z == 1) ? bk : bv;
  unsigned short* out = (z == 0) ? qo : (z == 1) ? ko : vto;
  // q gets 1/sqrt(dk) * log2(e) so softmax runs in exp2 domain
  const float scale = (z == 0) ? 0.18033688011f : 1.0f;
  gemm128<1, 0>(X, W, bb, out, scale, (z == 2) ? 1 : 0, blockIdx.x, blockIdx.y);
}

__global__ __launch_bounds__(256, 2) void out_proj(
    const unsigned short* __restrict__ X, const float* __restrict__ W,
    const float* __restrict__ bias, float* __restrict__ out)
{
  gemm128<0, 1>(X, W, bias, out, 1.0f, 0, blockIdx.x, blockIdx.y);
}

// ---------------------------------------------------------------------------
// Flash attention v6: 32 q-rows/wave, 4 waves (256 thr), grid (32,24).
// Rationale: K/V fragment reads (16 KB/wave/tile) are independent of rows/
// wave -> doubling rows/wave cuts LDS bytes per unit work ~1.6x (LDS pipe
// was the saturated resource). Single-buffer K/V + reg prefetch + raw
// barriers (r8 structure). LDS: K 8K @0, V 8K @8192, P/wave [32][72] @16384.
// ---------------------------------------------------------------------------
__global__ __launch_bounds__(256, 4) void attn_fwd(
    const unsigned short* qw, const unsigned short* __restrict__ kw,
    const unsigned short* __restrict__ vtw, unsigned short* ow)
{
  __shared__ char LDS[34816];

  const int tid = threadIdx.x, wave = tid >> 6, lane = tid & 63;
  const int g = lane >> 4, lo = lane & 15;
  const int bh = blockIdx.y, b = bh / 12, hh = bh % 12;
  const int q0 = blockIdx.x * 128 + wave * 32;

  // Q A-fragments: aq[m][s]: rows q0+m*16+lo, k-dims s*32+g*8..+7
  short8 aq[2][2];
#pragma unroll
  for (int m = 0; m < 2; ++m)
#pragma unroll
    for (int s = 0; s < 2; ++s)
      aq[m][s] = *(const short8*)(qw + (size_t)(b * 4096 + q0 + m * 16 + lo) * 768
                                  + hh * 64 + s * 32 + g * 8);

  const f32x4 vzero = {0.f, 0.f, 0.f, 0.f};
  float mx[2][4];
  f32x4 lacc[2];
  f32x4 oacc[2][4];
#pragma unroll
  for (int m = 0; m < 2; ++m) {
    lacc[m] = vzero;
#pragma unroll
    for (int r = 0; r < 4; ++r) mx[m][r] = -1e30f;
#pragma unroll
    for (int n = 0; n < 4; ++n) oacc[m][n] = vzero;
  }

  short8 bone;  // bf16 1.0 B-fragment (row-sum via MFMA)
#pragma unroll
  for (int j = 0; j < 8; ++j) bone[j] = (short)0x3F80;

  // per-lane base offsets; all loop accesses are base + compile-time imm
  const int rsw = (lo & 7) << 4;
  const int rb0 = lo * 128 + ((g * 16) ^ rsw);
  const int rb1 = lo * 128 + ((64 + g * 16) ^ rsw);
  char* const Kr0 = LDS + rb0;                  // + n*2048
  char* const Kr1 = LDS + rb1;
  char* const Vr0 = LDS + 8192 + rb0;           // + nd*2048
  char* const Vr1 = LDS + 8192 + rb1;
  // P per wave: [32][72] u16 (144B rows). write: row m*16+g*4+r, col n*16+lo
  char* const Pwr = LDS + 16384 + wave * 4608 + (g * 4) * 144 + lo * 2;  // +m*2304+r*144+n*32
  char* const Prd = LDS + 16384 + wave * 4608 + lo * 144 + g * 16;       // +m*2304+{0,64}

  // staging: 256 threads cover 64 rows x 4 x 32B (2 x 16B chunks each)
  const int srow = tid >> 2;
  const int sc = (tid & 3) * 2;
  const unsigned short* krow = kw + ((size_t)b * 4096 + srow) * 768 + hh * 64 + sc * 8;
  const unsigned short* vrow = vtw + ((size_t)bh * 64 + srow) * 4096 + sc * 8;
  const int sd0 = srow * 128 + ((sc * 16) ^ ((srow & 7) << 4));
  const int sd1 = sd0 ^ 16;  // (sc+1) chunk: sc even -> bit4 flip
  char* const Ksd0 = LDS + sd0;
  char* const Ksd1 = LDS + sd1;
  char* const Vsd0 = LDS + 8192 + sd0;
  char* const Vsd1 = LDS + 8192 + sd1;

  // prefetch tile 0 into regs
  short8 kl0 = *(const short8*)(krow);
  short8 kl1 = *(const short8*)(krow + 8);
  short8 vl0 = *(const short8*)(vrow);
  short8 vl1 = *(const short8*)(vrow + 8);

  for (int kv0 = 0; kv0 < 4096; kv0 += 64) {
    // WAR barrier (raw: vmcnt NOT drained -> prefetched loads stay in flight)
    asm volatile("s_waitcnt lgkmcnt(0)" ::: "memory");
    __builtin_amdgcn_s_barrier();
    *(short8*)Ksd0 = kl0;   // compiler inserts vmcnt wait (data dep)
    *(short8*)Ksd1 = kl1;
    *(short8*)Vsd0 = vl0;
    *(short8*)Vsd1 = vl1;
    if (kv0 + 64 < 4096) {  // prefetch next tile
      kl0 = *(const short8*)(krow + (size_t)(kv0 + 64) * 768);
      kl1 = *(const short8*)(krow + (size_t)(kv0 + 64) * 768 + 8);
      vl0 = *(const short8*)(vrow + kv0 + 64);
      vl1 = *(const short8*)(vrow + kv0 + 64 + 8);
    }
    asm volatile("s_waitcnt lgkmcnt(0)" ::: "memory");
    __builtin_amdgcn_s_barrier();
    __builtin_amdgcn_sched_barrier(0);

    // ---- per m-half: S = q@k^T, softmax, P write (m1 QK overlaps m0 VALU) ----
#pragma unroll
    for (int m = 0; m < 2; ++m) {
      f32x4 sa[4];
#pragma unroll
      for (int n = 0; n < 4; ++n) {
        short8 bk0 = *(const short8*)(Kr0 + n * 2048);
        short8 bk1 = *(const short8*)(Kr1 + n * 2048);
        f32x4 t = vzero;
        t = __builtin_amdgcn_mfma_f32_16x16x32_bf16(aq[m][0], bk0, t, 0, 0, 0);
        t = __builtin_amdgcn_mfma_f32_16x16x32_bf16(aq[m][1], bk1, t, 0, 0, 0);
        sa[n] = t;
      }
#pragma unroll
      for (int r = 0; r < 4; ++r) {
        float pm = fmaxf(fmaxf(sa[0][r], sa[1][r]), fmaxf(sa[2][r], sa[3][r]));
        pm = max16_dpp(pm);
        if (pm > mx[m][r] + 8.f) {  // defer-max
          const float fr = __builtin_amdgcn_exp2f(mx[m][r] - pm);
          mx[m][r] = pm;
          lacc[m][r] *= fr;
#pragma unroll
          for (int nd = 0; nd < 4; ++nd) oacc[m][nd][r] *= fr;
        }
#pragma unroll
        for (int n = 0; n < 4; ++n) {
          const float pv = __builtin_amdgcn_exp2f(sa[n][r] - mx[m][r]);
          *(unsigned short*)(Pwr + m * 2304 + r * 144 + n * 32) =
              (unsigned short)(__float_as_uint(pv) >> 16);
        }
      }
    }

    // ---- O += P @ V ; l += P @ 1 (V-frags shared across both m) ----
    short8 ap[2][2];
#pragma unroll
    for (int m = 0; m < 2; ++m) {
      ap[m][0] = *(const short8*)(Prd + m * 2304);
      ap[m][1] = *(const short8*)(Prd + m * 2304 + 64);
    }
#pragma unroll
    for (int nd = 0; nd < 4; ++nd) {
      short8 bv0 = *(const short8*)(Vr0 + nd * 2048);
      short8 bv1 = *(const short8*)(Vr1 + nd * 2048);
#pragma unroll
      for (int m = 0; m < 2; ++m) {
        oacc[m][nd] = __builtin_amdgcn_mfma_f32_16x16x32_bf16(ap[m][0], bv0, oacc[m][nd], 0, 0, 0);
        oacc[m][nd] = __builtin_amdgcn_mfma_f32_16x16x32_bf16(ap[m][1], bv1, oacc[m][nd], 0, 0, 0);
      }
    }
#pragma unroll
    for (int m = 0; m < 2; ++m) {
      lacc[m] = __builtin_amdgcn_mfma_f32_16x16x32_bf16(ap[m][0], bone, lacc[m], 0, 0, 0);
      lacc[m] = __builtin_amdgcn_mfma_f32_16x16x32_bf16(ap[m][1], bone, lacc[m], 0, 0, 0);
    }
  }

  // epilogue: normalize (RNE), store merged-head bf16 [8192][768] (in-place)
#pragma unroll
  for (int m = 0; m < 2; ++m)
#pragma unroll
    for (int r = 0; r < 4; ++r) {
      const float inv = 1.f / lacc[m][r];
      const size_t rowoff =
          (size_t)(b * 4096 + q0 + m * 16 + g * 4 + r) * 768 + hh * 64;
#pragma unroll
      for (int nd = 0; nd < 4; ++nd)
        ow[rowoff + nd * 16 + lo] = f2bf(oacc[m][nd][r] * inv);
    }
}

extern "C" void kernel_launch(void* const* d_in, const int* in_sizes, int n_in,
                              void* d_out, int out_size, void* d_ws, size_t ws_size,
                              hipStream_t stream) {
  (void)in_sizes; (void)n_in; (void)out_size; (void)ws_size;
  const float* Qi = (const float*)d_in[0];
  const float* Ki = (const float*)d_in[1];
  const float* Vi = (const float*)d_in[2];
  const float* Wq = (const float*)d_in[3];
  const float* bq = (const float*)d_in[4];
  const float* Wk = (const float*)d_in[5];
  const float* bk = (const float*)d_in[6];
  const float* Wv = (const float*)d_in[7];
  const float* bv = (const float*)d_in[8];
  const float* Wo = (const float*)d_in[9];
  const float* bo = (const float*)d_in[10];

  // ws: q bf16 + v^T bf16 (25.2 MB). k bf16 scratch in d_out's first 12.6 MB
  // (overwritten by out_proj's fp32 output at the end, stream-ordered).
  // Attention output reuses qw in place.
  unsigned short* ws = (unsigned short*)d_ws;
  const size_t NTOK = 8192u * 768u;  // 6291456
  unsigned short* qw  = ws;
  unsigned short* vtw = ws + NTOK;
  unsigned short* kwp = (unsigned short*)d_out;

  qkv_proj<<<dim3(64, 6, 3), 256, 0, stream>>>(Qi, Ki, Vi, Wq, bq, Wk, bk,
                                               Wv, bv, qw, kwp, vtw);
  attn_fwd<<<dim3(32, 24, 1), 256, 0, stream>>>(qw, kwp, vtw, qw);
  out_proj<<<dim3(64, 6, 1), 256, 0, stream>>>(qw, Wo, bo, (float*)d_out);
}